// Round 2
// baseline (769.614 us; speedup 1.0000x reference)
//
#include <hip/hip_runtime.h>
#include <math.h>

// Problem constants (from reference): B=2, T=2048, C=1024, H=16, hd=64, window=512.
#define BATCH 2
#define TSEQ  2048
#define CDIM  1024
#define NH    16
#define HD    64
#define WIN   512
#define MROWS (BATCH * TSEQ)   // 4096 rows of x

// ---------------------------------------------------------------------------
// GEMM: C[m,n] = sum_k A[m,k] * W[n,k]   (y = x @ W^T, W row-major [n_out,k])
// Tile 128x128, BK=16, 256 threads, 8x8 microtile per thread. fp32 VALU.
// PERM=1: scatter-store C into [B, H, T, hd] layout (for Q/K/V).
// PERM=0: plain row-major [M, C] store.
// blockIdx.z selects one of up to 3 (W, out) pairs so QKV runs in one launch.
// ---------------------------------------------------------------------------
template <int PERM>
__global__ __launch_bounds__(256) void gemm_xwT(
    const float* __restrict__ A,
    const float* __restrict__ Wa, const float* __restrict__ Wb, const float* __restrict__ Wc,
    float* __restrict__ Oa, float* __restrict__ Ob, float* __restrict__ Oc)
{
    constexpr int K = CDIM;
    const float* W = (blockIdx.z == 0) ? Wa : (blockIdx.z == 1 ? Wb : Wc);
    float*       C = (blockIdx.z == 0) ? Oa : (blockIdx.z == 1 ? Ob : Oc);

    // Transposed LDS tiles: As[k][m], Bs[k][n]. Stride 132 floats keeps float4
    // alignment (132*4 % 16 == 0) and breaks power-of-2 bank strides.
    __shared__ float As[16][132];
    __shared__ float Bs[16][132];

    const int tid = threadIdx.x;
    const int m0  = blockIdx.x * 128;
    const int n0  = blockIdx.y * 128;
    const int tm  = (tid >> 4) << 3;   // 0..120
    const int tn  = (tid & 15) << 3;   // 0..120

    float acc[8][8];
#pragma unroll
    for (int i = 0; i < 8; ++i)
#pragma unroll
        for (int j = 0; j < 8; ++j) acc[i][j] = 0.f;

    for (int k0 = 0; k0 < K; k0 += 16) {
        // Stage A and W tiles (transposed) : 512 float4 each / 256 threads.
#pragma unroll
        for (int u = 0; u < 2; ++u) {
            const int idx = tid + u * 256;      // 0..511
            const int r   = idx >> 2;           // tile row 0..127
            const int kc  = (idx & 3) << 2;     // 0,4,8,12
            const float4 av = *(const float4*)&A[(size_t)(m0 + r) * K + k0 + kc];
            const float4 bv = *(const float4*)&W[(size_t)(n0 + r) * K + k0 + kc];
            As[kc + 0][r] = av.x; As[kc + 1][r] = av.y; As[kc + 2][r] = av.z; As[kc + 3][r] = av.w;
            Bs[kc + 0][r] = bv.x; Bs[kc + 1][r] = bv.y; Bs[kc + 2][r] = bv.z; Bs[kc + 3][r] = bv.w;
        }
        __syncthreads();

#pragma unroll
        for (int kk = 0; kk < 16; ++kk) {
            float a[8], b[8];
            *(float4*)&a[0] = *(const float4*)&As[kk][tm];
            *(float4*)&a[4] = *(const float4*)&As[kk][tm + 4];
            *(float4*)&b[0] = *(const float4*)&Bs[kk][tn];
            *(float4*)&b[4] = *(const float4*)&Bs[kk][tn + 4];
#pragma unroll
            for (int i = 0; i < 8; ++i)
#pragma unroll
                for (int j = 0; j < 8; ++j)
                    acc[i][j] = fmaf(a[i], b[j], acc[i][j]);
        }
        __syncthreads();
    }

    if (PERM) {
        // n -> (h, d); store into [B, H, T, hd]. tn%64 <= 56, so h constant per thread.
        const int n = n0 + tn;
        const int h = n >> 6;
        const int d = n & 63;
#pragma unroll
        for (int i = 0; i < 8; ++i) {
            const int m = m0 + tm + i;
            const int b = m >> 11;           // / TSEQ
            const int t = m & (TSEQ - 1);
            float* dst = &C[(((size_t)b * NH + h) * TSEQ + t) * HD + d];
            *(float4*)&dst[0] = make_float4(acc[i][0], acc[i][1], acc[i][2], acc[i][3]);
            *(float4*)&dst[4] = make_float4(acc[i][4], acc[i][5], acc[i][6], acc[i][7]);
        }
    } else {
#pragma unroll
        for (int i = 0; i < 8; ++i) {
            const int m = m0 + tm + i;
            float* dst = &C[(size_t)m * CDIM + n0 + tn];
            *(float4*)&dst[0] = make_float4(acc[i][0], acc[i][1], acc[i][2], acc[i][3]);
            *(float4*)&dst[4] = make_float4(acc[i][4], acc[i][5], acc[i][6], acc[i][7]);
        }
    }
}

// ---------------------------------------------------------------------------
// Sliding-window flash attention, fp32. One block = one (b,h) x 64 q-rows.
// 256 threads: thread(ty,tx) owns 4x4 of the 64x64 score / output tile.
// Online softmax; K-buffer is reused for the P matrix (union) to keep LDS at
// 3*64*68*4 = 52.2 KB -> 3 blocks/CU.
// ---------------------------------------------------------------------------
__global__ __launch_bounds__(256) void attn_swin(
    const float* __restrict__ Q, const float* __restrict__ K,
    const float* __restrict__ V, float* __restrict__ Y)
{
    __shared__ float Qs[64][68];   // [d][q]  (transposed)
    __shared__ float KPs[64][68];  // as K: [d][k] (transposed); as P: [k][q]
    __shared__ float Vs[64][68];   // [k][d]  (natural)

    const int tid = threadIdx.x;
    const int q0  = (blockIdx.x & 31) * 64;     // T/64 = 32 q-tiles
    const int bh  = blockIdx.x >> 5;            // 0..31  (= b*NH + h)

    const float* Qb = Q + (size_t)bh * TSEQ * HD;
    const float* Kb = K + (size_t)bh * TSEQ * HD;
    const float* Vb = V + (size_t)bh * TSEQ * HD;

    const int tx = tid & 15;      // key / d column group
    const int ty = tid >> 4;      // q row group
    const int qm = ty * 4;
    const int kn = tx * 4;

    // Load Q tile transposed: Qs[d][q].
    {
#pragma unroll
        for (int r = 0; r < 4; ++r) {
            const int t = (tid >> 4) + r * 16;
            const float4 v = *(const float4*)&Qb[(size_t)(q0 + t) * HD + tx * 4];
            Qs[tx * 4 + 0][t] = v.x; Qs[tx * 4 + 1][t] = v.y;
            Qs[tx * 4 + 2][t] = v.z; Qs[tx * 4 + 3][t] = v.w;
        }
    }

    float O[4][4];
    float mrow[4], lrow[4];
#pragma unroll
    for (int i = 0; i < 4; ++i) {
        mrow[i] = -1e30f; lrow[i] = 0.f;
#pragma unroll
        for (int j = 0; j < 4; ++j) O[i][j] = 0.f;
    }

    int kbeg = q0 - (WIN - 1); if (kbeg < 0) kbeg = 0; kbeg &= ~63;
    int kend = q0 + 64 + (WIN - 1); if (kend > TSEQ) kend = TSEQ;
    const float scale = 0.125f;   // 1/sqrt(64)

    for (int k0 = kbeg; k0 < kend; k0 += 64) {
        __syncthreads();   // prev PV done reading KPs/Vs
        // Stage K (transposed) and V (natural) tiles. All rows in-bounds.
#pragma unroll
        for (int r = 0; r < 4; ++r) {
            const int t = (tid >> 4) + r * 16;
            const float4 kv = *(const float4*)&Kb[(size_t)(k0 + t) * HD + tx * 4];
            KPs[tx * 4 + 0][t] = kv.x; KPs[tx * 4 + 1][t] = kv.y;
            KPs[tx * 4 + 2][t] = kv.z; KPs[tx * 4 + 3][t] = kv.w;
            const float4 vv = *(const float4*)&Vb[(size_t)(k0 + t) * HD + tx * 4];
            *(float4*)&Vs[t][tx * 4] = vv;
        }
        __syncthreads();

        // S = Q . K^T  (64 d-steps, 16 FMA each)
        float S[4][4];
#pragma unroll
        for (int i = 0; i < 4; ++i)
#pragma unroll
            for (int j = 0; j < 4; ++j) S[i][j] = 0.f;
#pragma unroll 8
        for (int d = 0; d < 64; ++d) {
            float4 qa = *(const float4*)&Qs[d][qm];
            float4 kb = *(const float4*)&KPs[d][kn];
            const float aq[4] = {qa.x, qa.y, qa.z, qa.w};
            const float bk[4] = {kb.x, kb.y, kb.z, kb.w};
#pragma unroll
            for (int i = 0; i < 4; ++i)
#pragma unroll
                for (int j = 0; j < 4; ++j)
                    S[i][j] = fmaf(aq[i], bk[j], S[i][j]);
        }

        // scale + window mask: valid iff |i-j| <= WIN-1
#pragma unroll
        for (int i = 0; i < 4; ++i) {
            const int ig = q0 + qm + i;
#pragma unroll
            for (int j = 0; j < 4; ++j) {
                const int jg = k0 + kn + j;
                const bool ok = (unsigned)(ig - jg + (WIN - 1)) < (unsigned)(2 * WIN - 1);
                S[i][j] = ok ? S[i][j] * scale : -1e30f;
            }
        }

        // Online softmax (row stats shared across the 16 tx lanes of each row).
        float Pv[4][4];
#pragma unroll
        for (int i = 0; i < 4; ++i) {
            float mx = fmaxf(fmaxf(S[i][0], S[i][1]), fmaxf(S[i][2], S[i][3]));
#pragma unroll
            for (int o = 1; o < 16; o <<= 1) mx = fmaxf(mx, __shfl_xor(mx, o, 16));
            const float mnew = fmaxf(mrow[i], mx);
            const float f = __expf(mrow[i] - mnew);
            float ps = 0.f;
#pragma unroll
            for (int j = 0; j < 4; ++j) {
                const float p = (S[i][j] > -1e29f) ? __expf(S[i][j] - mnew) : 0.f;
                Pv[i][j] = p; ps += p;
            }
#pragma unroll
            for (int o = 1; o < 16; o <<= 1) ps += __shfl_xor(ps, o, 16);
            lrow[i] = lrow[i] * f + ps;
            mrow[i] = mnew;
#pragma unroll
            for (int j = 0; j < 4; ++j) O[i][j] *= f;
        }

        __syncthreads();   // everyone done reading KPs as K
        // Write P transposed into the K buffer: KPs[k][q]
#pragma unroll
        for (int j = 0; j < 4; ++j)
            *(float4*)&KPs[kn + j][qm] = make_float4(Pv[0][j], Pv[1][j], Pv[2][j], Pv[3][j]);
        __syncthreads();

        // O += P^T-view GEMM: O[i][j] += sum_k P[k][qm+i] * V[k][kn+j]
#pragma unroll 8
        for (int k = 0; k < 64; ++k) {
            float4 pa = *(const float4*)&KPs[k][qm];
            float4 vb = *(const float4*)&Vs[k][kn];
            const float ap[4] = {pa.x, pa.y, pa.z, pa.w};
            const float bv[4] = {vb.x, vb.y, vb.z, vb.w};
#pragma unroll
            for (int i = 0; i < 4; ++i)
#pragma unroll
                for (int j = 0; j < 4; ++j)
                    O[i][j] = fmaf(ap[i], bv[j], O[i][j]);
        }
    }

    // Epilogue: normalize and store y in [B, T, H*hd] layout for the final GEMM.
    const int b = bh >> 4;
    const int h = bh & 15;
#pragma unroll
    for (int i = 0; i < 4; ++i) {
        const float inv = 1.f / lrow[i];
        const int t = q0 + qm + i;
        float* dst = &Y[((size_t)(b * TSEQ + t)) * CDIM + h * HD + kn];
        *(float4*)dst = make_float4(O[i][0] * inv, O[i][1] * inv, O[i][2] * inv, O[i][3] * inv);
    }
}

// ---------------------------------------------------------------------------
extern "C" void kernel_launch(void* const* d_in, const int* in_sizes, int n_in,
                              void* d_out, int out_size, void* d_ws, size_t ws_size,
                              hipStream_t stream)
{
    const float* x  = (const float*)d_in[0];
    const float* Wq = (const float*)d_in[1];
    const float* Wk = (const float*)d_in[2];
    const float* Wv = (const float*)d_in[3];
    const float* Wo = (const float*)d_in[4];
    float* out = (float*)d_out;

    const size_t elems = (size_t)MROWS * CDIM;   // 4,194,304 floats = 16 MiB
    float* qb = (float*)d_ws;                    // [B,H,T,hd]
    float* kb = qb + elems;
    float* vb = kb + elems;
    float* yb = vb + elems;                      // [B,T,C] attention output

    // QKV projections (one launch, z selects W/out)
    gemm_xwT<1><<<dim3(MROWS / 128, CDIM / 128, 3), 256, 0, stream>>>(
        x, Wq, Wk, Wv, qb, kb, vb);

    // Sliding-window attention
    attn_swin<<<dim3(BATCH * NH * (TSEQ / 64)), 256, 0, stream>>>(qb, kb, vb, yb);

    // Output projection -> d_out
    gemm_xwT<0><<<dim3(MROWS / 128, CDIM / 128, 1), 256, 0, stream>>>(
        yb, Wo, Wo, Wo, out, out, out);
}

// Round 5
// 207.237 us; speedup vs baseline: 3.7137x; 3.7137x over previous
//
#include <hip/hip_runtime.h>

// Problem constants: B=2, T=2048, C=1024, H=16, hd=64, window=512.
#define BATCH 2
#define TSEQ  2048
#define CDIM  1024
#define NH    16
#define HD    64
#define WIN   512
#define MROWS (BATCH * TSEQ)   // 4096

typedef __attribute__((ext_vector_type(8))) short short8;   // 8 bf16 (4 VGPRs)
typedef __attribute__((ext_vector_type(4))) float f32x4;

static __device__ __forceinline__ unsigned short f2bf(float f) {
    union { float f; unsigned u; } v; v.f = f;
    unsigned r = v.u + 0x7FFFu + ((v.u >> 16) & 1u);   // RNE
    return (unsigned short)(r >> 16);
}

static __device__ __forceinline__ f32x4 mfma16(short8 a, short8 b, f32x4 c) {
    return __builtin_amdgcn_mfma_f32_16x16x32_bf16(a, b, c, 0, 0, 0);
}

// ---------------------------------------------------------------------------
// fp32 -> bf16 conversion for x and the four weight matrices (8M elems, 8/thr)
// ---------------------------------------------------------------------------
__global__ __launch_bounds__(256) void convert_inputs(
    const float* __restrict__ x,  const float* __restrict__ wq,
    const float* __restrict__ wk, const float* __restrict__ wv,
    const float* __restrict__ wo,
    unsigned short* __restrict__ xb,  unsigned short* __restrict__ wqb,
    unsigned short* __restrict__ wkb, unsigned short* __restrict__ wvb,
    unsigned short* __restrict__ wob)
{
    const long i8 = (long)(blockIdx.x * 256 + threadIdx.x) * 8;
    const long XN = (long)MROWS * CDIM;      // 4M
    const long WN = (long)CDIM * CDIM;       // 1M
    const float* src; unsigned short* dst; long off;
    if (i8 < XN) { src = x; dst = xb; off = i8; }
    else {
        long j = i8 - XN; int w = (int)(j / WN); off = j - (long)w * WN;
        src = (w == 0) ? wq : (w == 1) ? wk : (w == 2) ? wv : wo;
        dst = (w == 0) ? wqb : (w == 1) ? wkb : (w == 2) ? wvb : wob;
    }
    const float4 a = *(const float4*)&src[off];
    const float4 b = *(const float4*)&src[off + 4];
    uint4 o;
    o.x = f2bf(a.x) | ((unsigned)f2bf(a.y) << 16);
    o.y = f2bf(a.z) | ((unsigned)f2bf(a.w) << 16);
    o.z = f2bf(b.x) | ((unsigned)f2bf(b.y) << 16);
    o.w = f2bf(b.z) | ((unsigned)f2bf(b.w) << 16);
    *(uint4*)&dst[off] = o;
}

// ---------------------------------------------------------------------------
// bf16 MFMA GEMM: C[m,n] = sum_k A[m,k]*W[n,k]   (y = x @ W^T), K=1024.
// 128x128 tile, BK=32, 4 waves, each wave 64x64 via 4x4 frags of 16x16x32.
// MODE 0: fp32 row-major out [M,1024]  (single W/out, z=0)
// MODE 1: bf16 out; z=0,1 -> [b,h,t,d] (Q,K); z=2 -> [b,h,d,t] (V transposed)
// Register-prefetched staging (issue next tile's loads before compute).
// LDS pad: rows of 40 bf16 (80B) -> 2-way bank aliasing only (free).
// ---------------------------------------------------------------------------
template <int MODE>
__global__ __launch_bounds__(256) void gemm_bf16(
    const unsigned short* __restrict__ A,
    const unsigned short* __restrict__ W0, const unsigned short* __restrict__ W1,
    const unsigned short* __restrict__ W2,
    void* __restrict__ O0, void* __restrict__ O1, void* __restrict__ O2)
{
    constexpr int KD = CDIM;
    __shared__ unsigned short As[128][40];
    __shared__ unsigned short Bs[128][40];

    const int tid  = threadIdx.x;
    const int lane = tid & 63;
    const int w    = tid >> 6;
    const int wm   = (w >> 1) * 64;
    const int wn   = (w & 1) * 64;
    const int m0   = blockIdx.x * 128;
    const int n0   = blockIdx.y * 128;
    const unsigned short* Wm = (blockIdx.z == 0) ? W0 : (blockIdx.z == 1) ? W1 : W2;

    // staging: 512 16B-chunks per operand; thread t handles chunks t and t+256
    const int r0  = tid >> 2;            // rows 0..63 (+64 for 2nd chunk)
    const int ch0 = (tid & 3) * 8;       // elem offset 0/8/16/24
    const unsigned short* gA0 = A  + (size_t)(m0 + r0) * KD + ch0;
    const unsigned short* gA1 = gA0 + (size_t)64 * KD;
    const unsigned short* gB0 = Wm + (size_t)(n0 + r0) * KD + ch0;
    const unsigned short* gB1 = gB0 + (size_t)64 * KD;

    const f32x4 fz = {0.f, 0.f, 0.f, 0.f};
    f32x4 acc[4][4];
#pragma unroll
    for (int i = 0; i < 4; ++i)
#pragma unroll
        for (int j = 0; j < 4; ++j) acc[i][j] = fz;

    uint4 ra0 = *(const uint4*)gA0;
    uint4 ra1 = *(const uint4*)gA1;
    uint4 rb0 = *(const uint4*)gB0;
    uint4 rb1 = *(const uint4*)gB1;

    const int fr = lane & 15;
    const int fc = (lane >> 4) * 8;

    for (int kt = 0; kt < KD / 32; ++kt) {
        if (kt) __syncthreads();
        *(uint4*)&As[r0][ch0]      = ra0;
        *(uint4*)&As[r0 + 64][ch0] = ra1;
        *(uint4*)&Bs[r0][ch0]      = rb0;
        *(uint4*)&Bs[r0 + 64][ch0] = rb1;
        __syncthreads();
        if (kt + 1 < KD / 32) {
            const int ko = (kt + 1) * 32;
            ra0 = *(const uint4*)(gA0 + ko);
            ra1 = *(const uint4*)(gA1 + ko);
            rb0 = *(const uint4*)(gB0 + ko);
            rb1 = *(const uint4*)(gB1 + ko);
        }
        short8 af[4], bf[4];
#pragma unroll
        for (int mt = 0; mt < 4; ++mt)
            af[mt] = *(const short8*)&As[wm + mt * 16 + fr][fc];
#pragma unroll
        for (int nt = 0; nt < 4; ++nt)
            bf[nt] = *(const short8*)&Bs[wn + nt * 16 + fr][fc];
#pragma unroll
        for (int mt = 0; mt < 4; ++mt)
#pragma unroll
            for (int nt = 0; nt < 4; ++nt)
                acc[mt][nt] = mfma16(af[mt], bf[nt], acc[mt][nt]);
    }

    const int fg = lane >> 4;
    if constexpr (MODE == 0) {
        float* Out = (float*)O0;
#pragma unroll
        for (int mt = 0; mt < 4; ++mt) {
            const int row0 = m0 + wm + mt * 16 + fg * 4;
#pragma unroll
            for (int nt = 0; nt < 4; ++nt) {
                const int col = n0 + wn + nt * 16 + fr;
#pragma unroll
                for (int r = 0; r < 4; ++r)
                    Out[(size_t)(row0 + r) * CDIM + col] = acc[mt][nt][r];
            }
        }
    } else {
        unsigned short* Out = (unsigned short*)((blockIdx.z == 0) ? O0 : (blockIdx.z == 1) ? O1 : O2);
        const bool vmode = (blockIdx.z == 2);
#pragma unroll
        for (int mt = 0; mt < 4; ++mt) {
            const int row0 = m0 + wm + mt * 16 + fg * 4;
            const int b  = row0 >> 11;           // / TSEQ
            const int t0 = row0 & (TSEQ - 1);
#pragma unroll
            for (int nt = 0; nt < 4; ++nt) {
                const int col = n0 + wn + nt * 16 + fr;
                const int h = col >> 6, d = col & 63;
                if (!vmode) {
#pragma unroll
                    for (int r = 0; r < 4; ++r)
                        Out[(((size_t)b * NH + h) * TSEQ + (t0 + r)) * HD + d] =
                            f2bf(acc[mt][nt][r]);
                } else {
                    ushort4 pk;
                    pk.x = f2bf(acc[mt][nt][0]); pk.y = f2bf(acc[mt][nt][1]);
                    pk.z = f2bf(acc[mt][nt][2]); pk.w = f2bf(acc[mt][nt][3]);
                    *(ushort4*)&Out[(((size_t)b * NH + h) * HD + d) * TSEQ + t0] = pk;
                }
            }
        }
    }
}

// ---------------------------------------------------------------------------
// Sliding-window flash attention, bf16 MFMA. Block = (q-tile of 64) x (b,h).
// 4 waves; wave w owns q-rows [q0+w*16, +16). K tile 64x64 in LDS [key][d],
// V tile from pre-transposed [b,h,d,t] global into LDS [d][key] -> contiguous
// B-frags for PV. P transposed lane->A-frag layout via per-wave LDS strip.
// fp32 online softmax; MFMA accumulators fp32.
// ---------------------------------------------------------------------------
__global__ __launch_bounds__(256) void attn_mfma(
    const unsigned short* __restrict__ Qg, const unsigned short* __restrict__ Kg,
    const unsigned short* __restrict__ Vg, unsigned short* __restrict__ Y)
{
    __shared__ unsigned short Ks[64][72];      // [key][d]   pad->2-way only
    __shared__ unsigned short Vs[64][72];      // [d][key]
    __shared__ unsigned short Ps[4][16][72];   // per-wave P strip [q][key]

    const int tid  = threadIdx.x;
    const int lane = tid & 63;
    const int w    = tid >> 6;
    const int q0   = blockIdx.x * 64;
    const int bh   = blockIdx.y;

    const unsigned short* Qb = Qg + (size_t)bh * TSEQ * HD;
    const unsigned short* Kb = Kg + (size_t)bh * TSEQ * HD;
    const unsigned short* Vb = Vg + (size_t)bh * HD * TSEQ;   // [d][t]

    const int fr = lane & 15;
    const int fg = lane >> 4;

    // Q fragments held in registers for the whole kernel.
    const short8 qa0 = *(const short8*)&Qb[(size_t)(q0 + w * 16 + fr) * HD + fg * 8];
    const short8 qa1 = *(const short8*)&Qb[(size_t)(q0 + w * 16 + fr) * HD + 32 + fg * 8];

    const f32x4 fz = {0.f, 0.f, 0.f, 0.f};
    f32x4 Oacc[4];
    float mrow[4], lsum[4];
#pragma unroll
    for (int i = 0; i < 4; ++i) { Oacc[i] = fz; mrow[i] = -1e30f; lsum[i] = 0.f; }

    int kbeg = q0 - (WIN - 1); if (kbeg < 0) kbeg = 0; kbeg &= ~63;
    int kend = q0 + 64 + (WIN - 1); if (kend > TSEQ) kend = TSEQ;

    // staging: 512 chunks of 16B per tile; thread t -> chunks t, t+256
    const int sr = tid >> 3;            // rows 0..31 (+32)
    const int sc = (tid & 7) * 8;       // elem offset in 64-wide row
    uint4 kreg0 = *(const uint4*)&Kb[(size_t)(kbeg + sr) * HD + sc];
    uint4 kreg1 = *(const uint4*)&Kb[(size_t)(kbeg + sr + 32) * HD + sc];
    uint4 vreg0 = *(const uint4*)&Vb[(size_t)sr * TSEQ + kbeg + sc];
    uint4 vreg1 = *(const uint4*)&Vb[(size_t)(sr + 32) * TSEQ + kbeg + sc];

    const float scale = 0.125f;   // 1/sqrt(64)

    for (int k0 = kbeg; k0 < kend; k0 += 64) {
        if (k0 != kbeg) __syncthreads();   // previous tile's reads done
        *(uint4*)&Ks[sr][sc]      = kreg0;
        *(uint4*)&Ks[sr + 32][sc] = kreg1;
        *(uint4*)&Vs[sr][sc]      = vreg0;
        *(uint4*)&Vs[sr + 32][sc] = vreg1;
        __syncthreads();
        if (k0 + 64 < kend) {              // prefetch next tile into regs
            kreg0 = *(const uint4*)&Kb[(size_t)(k0 + 64 + sr) * HD + sc];
            kreg1 = *(const uint4*)&Kb[(size_t)(k0 + 96 + sr) * HD + sc];
            vreg0 = *(const uint4*)&Vb[(size_t)sr * TSEQ + k0 + 64 + sc];
            vreg1 = *(const uint4*)&Vb[(size_t)(sr + 32) * TSEQ + k0 + 64 + sc];
        }

        // S = Q.K^T : 4 key-blocks x 2 d-halves
        f32x4 S[4];
#pragma unroll
        for (int nt = 0; nt < 4; ++nt) {
            const short8 kb0 = *(const short8*)&Ks[nt * 16 + fr][fg * 8];
            const short8 kb1 = *(const short8*)&Ks[nt * 16 + fr][32 + fg * 8];
            f32x4 s = fz;
            s = mfma16(qa0, kb0, s);
            s = mfma16(qa1, kb1, s);
            S[nt] = s;
        }

        // online softmax per row (rows fg*4+r, stats shared across 16 lanes)
        float p[4][4], fsc[4];
#pragma unroll
        for (int r = 0; r < 4; ++r) {
            const int irow = q0 + w * 16 + fg * 4 + r;
            float sv[4];
            float mx = -1e30f;
#pragma unroll
            for (int nt = 0; nt < 4; ++nt) {
                const int jcol = k0 + nt * 16 + fr;
                const bool ok = (unsigned)(irow - jcol + (WIN - 1)) < (unsigned)(2 * WIN - 1);
                const float v = ok ? S[nt][r] * scale : -1e30f;
                sv[nt] = v;
                mx = fmaxf(mx, v);
            }
#pragma unroll
            for (int o = 1; o < 16; o <<= 1) mx = fmaxf(mx, __shfl_xor(mx, o, 16));
            const float mnew = fmaxf(mrow[r], mx);
            const float f = __expf(mrow[r] - mnew);
            float ps = 0.f;
#pragma unroll
            for (int nt = 0; nt < 4; ++nt) {
                const float pv = (sv[nt] > -1e29f) ? __expf(sv[nt] - mnew) : 0.f;
                p[r][nt] = pv; ps += pv;
            }
#pragma unroll
            for (int o = 1; o < 16; o <<= 1) ps += __shfl_xor(ps, o, 16);
            lsum[r] = lsum[r] * f + ps;
            mrow[r] = mnew;
            fsc[r]  = f;
        }
#pragma unroll
        for (int db = 0; db < 4; ++db) {
            f32x4 t = Oacc[db];
            t[0] *= fsc[0]; t[1] *= fsc[1]; t[2] *= fsc[2]; t[3] *= fsc[3];
            Oacc[db] = t;
        }

        // P -> per-wave LDS strip (bf16), then PV via MFMA.
#pragma unroll
        for (int r = 0; r < 4; ++r)
#pragma unroll
            for (int nt = 0; nt < 4; ++nt)
                Ps[w][fg * 4 + r][nt * 16 + fr] = f2bf(p[r][nt]);

        const short8 pa0 = *(const short8*)&Ps[w][fr][fg * 8];
        const short8 pa1 = *(const short8*)&Ps[w][fr][32 + fg * 8];
#pragma unroll
        for (int db = 0; db < 4; ++db) {
            const short8 vb0 = *(const short8*)&Vs[db * 16 + fr][fg * 8];
            const short8 vb1 = *(const short8*)&Vs[db * 16 + fr][32 + fg * 8];
            Oacc[db] = mfma16(pa0, vb0, Oacc[db]);
            Oacc[db] = mfma16(pa1, vb1, Oacc[db]);
        }
    }

    // epilogue: normalize, store y [B,T,C] bf16
    const int b = bh >> 4, h = bh & 15;
    float inv[4];
#pragma unroll
    for (int r = 0; r < 4; ++r) inv[r] = 1.f / lsum[r];
#pragma unroll
    for (int db = 0; db < 4; ++db)
#pragma unroll
        for (int r = 0; r < 4; ++r) {
            const int t = q0 + w * 16 + fg * 4 + r;
            Y[(size_t)(b * TSEQ + t) * CDIM + h * HD + db * 16 + fr] =
                f2bf(Oacc[db][r] * inv[r]);
        }
}

// ---------------------------------------------------------------------------
extern "C" void kernel_launch(void* const* d_in, const int* in_sizes, int n_in,
                              void* d_out, int out_size, void* d_ws, size_t ws_size,
                              hipStream_t stream)
{
    const float* x  = (const float*)d_in[0];
    const float* Wq = (const float*)d_in[1];
    const float* Wk = (const float*)d_in[2];
    const float* Wv = (const float*)d_in[3];
    const float* Wo = (const float*)d_in[4];
    float* out = (float*)d_out;

    const size_t XN = (size_t)MROWS * CDIM;   // 4M elems
    const size_t WN = (size_t)CDIM * CDIM;    // 1M elems
    unsigned short* xb  = (unsigned short*)d_ws;
    unsigned short* wqb = xb  + XN;
    unsigned short* wkb = wqb + WN;
    unsigned short* wvb = wkb + WN;
    unsigned short* wob = wvb + WN;
    unsigned short* Qb  = wob + WN;           // [b,h,t,d]
    unsigned short* Kb  = Qb  + XN;           // [b,h,t,d]
    unsigned short* Vb  = Kb  + XN;           // [b,h,d,t]
    unsigned short* Yb  = Vb  + XN;           // [b,t,c]

    // 1) fp32 -> bf16 (x + 4 weight matrices)
    convert_inputs<<<dim3(4096), 256, 0, stream>>>(x, Wq, Wk, Wv, Wo,
                                                   xb, wqb, wkb, wvb, wob);
    // 2) QKV projections (z: 0=Q,1=K,2=V-transposed)
    gemm_bf16<1><<<dim3(MROWS / 128, CDIM / 128, 3), 256, 0, stream>>>(
        xb, wqb, wkb, wvb, Qb, Kb, Vb);
    // 3) sliding-window attention
    attn_mfma<<<dim3(TSEQ / 64, BATCH * NH), 256, 0, stream>>>(Qb, Kb, Vb, Yb);
    // 4) output projection -> fp32 out
    gemm_bf16<0><<<dim3(MROWS / 128, CDIM / 128, 1), 256, 0, stream>>>(
        Yb, wob, wob, wob, out, out, out);
}

// Round 7
// 200.221 us; speedup vs baseline: 3.8438x; 1.0350x over previous
//
#include <hip/hip_runtime.h>

// Problem constants: B=2, T=2048, C=1024, H=16, hd=64, window=512.
#define BATCH 2
#define TSEQ  2048
#define CDIM  1024
#define NH    16
#define HD    64
#define WIN   512
#define MROWS (BATCH * TSEQ)   // 4096
#define QBLK  128              // q-rows per attention block

typedef __attribute__((ext_vector_type(8))) short short8;   // 8 bf16 (4 VGPRs)
typedef __attribute__((ext_vector_type(4))) float f32x4;

static __device__ __forceinline__ unsigned short f2bf(float f) {
    union { float f; unsigned u; } v; v.f = f;
    unsigned r = v.u + 0x7FFFu + ((v.u >> 16) & 1u);   // RNE
    return (unsigned short)(r >> 16);
}

// packed fp32x2 -> bf16x2 (RNE via HW); src0 -> low half
static __device__ __forceinline__ unsigned cvtpk(float a, float b) {
    unsigned r;
    asm("v_cvt_pk_bf16_f32 %0, %1, %2" : "=v"(r) : "v"(a), "v"(b));
    return r;
}

static __device__ __forceinline__ f32x4 mfma16(short8 a, short8 b, f32x4 c) {
    return __builtin_amdgcn_mfma_f32_16x16x32_bf16(a, b, c, 0, 0, 0);
}

// load 8 elements at element-offset eoff as bf16x8; F32=1 converts fp32 src
template <int F32>
static __device__ __forceinline__ uint4 ld8(const void* p, size_t eoff) {
    if constexpr (F32) {
        const float* f = (const float*)p + eoff;
        const float4 a = *(const float4*)f;
        const float4 b = *(const float4*)(f + 4);
        uint4 o;
        o.x = cvtpk(a.x, a.y); o.y = cvtpk(a.z, a.w);
        o.z = cvtpk(b.x, b.y); o.w = cvtpk(b.z, b.w);
        return o;
    } else {
        return *(const uint4*)((const unsigned short*)p + eoff);
    }
}

// ---------------------------------------------------------------------------
// bf16 MFMA GEMM: C[m,n] = sum_k A[m,k]*W[n,k]  (y = x @ W^T), K=1024.
// 128x128 tile, BK=32, 4 waves, each wave 64x64 via 4x4 frags of 16x16x32.
// AF32/WF32: operand source dtype (fp32 converted to bf16 during staging).
// MODE 0: fp32 row-major out [M,1024] (z=0 only)
// MODE 1: bf16 out; z=0 -> Q [b,h,t,d] scaled by 1/8; z=1 -> K [b,h,t,d];
//         z=2 -> V transposed [b,h,d,t].
// ---------------------------------------------------------------------------
template <int MODE, int AF32, int WF32>
__global__ __launch_bounds__(256) void gemm_bf16(
    const void* __restrict__ A,
    const void* __restrict__ W0, const void* __restrict__ W1,
    const void* __restrict__ W2,
    void* __restrict__ O0, void* __restrict__ O1, void* __restrict__ O2)
{
    constexpr int KD = CDIM;
    __shared__ unsigned short As[128][40];
    __shared__ unsigned short Bs[128][40];

    const int tid  = threadIdx.x;
    const int lane = tid & 63;
    const int w    = tid >> 6;
    const int wm   = (w >> 1) * 64;
    const int wn   = (w & 1) * 64;
    const int m0   = blockIdx.x * 128;
    const int n0   = blockIdx.y * 128;
    const void* Wm = (blockIdx.z == 0) ? W0 : (blockIdx.z == 1) ? W1 : W2;

    // staging: 512 8-elem chunks per operand; thread t handles chunks t, t+256
    const int r0  = tid >> 2;            // rows 0..63 (+64 for 2nd chunk)
    const int ch0 = (tid & 3) * 8;       // elem offset 0/8/16/24
    const size_t aoff0 = (size_t)(m0 + r0) * KD + ch0;
    const size_t aoff1 = aoff0 + (size_t)64 * KD;
    const size_t boff0 = (size_t)(n0 + r0) * KD + ch0;
    const size_t boff1 = boff0 + (size_t)64 * KD;

    const f32x4 fz = {0.f, 0.f, 0.f, 0.f};
    f32x4 acc[4][4];
#pragma unroll
    for (int i = 0; i < 4; ++i)
#pragma unroll
        for (int j = 0; j < 4; ++j) acc[i][j] = fz;

    uint4 ra0 = ld8<AF32>(A, aoff0);
    uint4 ra1 = ld8<AF32>(A, aoff1);
    uint4 rb0 = ld8<WF32>(Wm, boff0);
    uint4 rb1 = ld8<WF32>(Wm, boff1);

    const int fr = lane & 15;
    const int fc = (lane >> 4) * 8;

    for (int kt = 0; kt < KD / 32; ++kt) {
        if (kt) __syncthreads();
        *(uint4*)&As[r0][ch0]      = ra0;
        *(uint4*)&As[r0 + 64][ch0] = ra1;
        *(uint4*)&Bs[r0][ch0]      = rb0;
        *(uint4*)&Bs[r0 + 64][ch0] = rb1;
        __syncthreads();
        if (kt + 1 < KD / 32) {
            const int ko = (kt + 1) * 32;
            ra0 = ld8<AF32>(A, aoff0 + ko);
            ra1 = ld8<AF32>(A, aoff1 + ko);
            rb0 = ld8<WF32>(Wm, boff0 + ko);
            rb1 = ld8<WF32>(Wm, boff1 + ko);
        }
        short8 af[4], bf[4];
#pragma unroll
        for (int mt = 0; mt < 4; ++mt)
            af[mt] = *(const short8*)&As[wm + mt * 16 + fr][fc];
#pragma unroll
        for (int nt = 0; nt < 4; ++nt)
            bf[nt] = *(const short8*)&Bs[wn + nt * 16 + fr][fc];
#pragma unroll
        for (int mt = 0; mt < 4; ++mt)
#pragma unroll
            for (int nt = 0; nt < 4; ++nt)
                acc[mt][nt] = mfma16(af[mt], bf[nt], acc[mt][nt]);
    }

    const int fg = lane >> 4;
    if constexpr (MODE == 0) {
        float* Out = (float*)O0;
#pragma unroll
        for (int mt = 0; mt < 4; ++mt) {
            const int row0 = m0 + wm + mt * 16 + fg * 4;
#pragma unroll
            for (int nt = 0; nt < 4; ++nt) {
                const int col = n0 + wn + nt * 16 + fr;
#pragma unroll
                for (int r = 0; r < 4; ++r)
                    Out[(size_t)(row0 + r) * CDIM + col] = acc[mt][nt][r];
            }
        }
    } else {
        unsigned short* Out = (unsigned short*)((blockIdx.z == 0) ? O0 : (blockIdx.z == 1) ? O1 : O2);
        const bool vmode = (blockIdx.z == 2);
        const float qs = (blockIdx.z == 0) ? 0.125f : 1.0f;   // fold 1/sqrt(hd) into Q
#pragma unroll
        for (int mt = 0; mt < 4; ++mt) {
            const int row0 = m0 + wm + mt * 16 + fg * 4;
            const int b  = row0 >> 11;           // / TSEQ
            const int t0 = row0 & (TSEQ - 1);
#pragma unroll
            for (int nt = 0; nt < 4; ++nt) {
                const int col = n0 + wn + nt * 16 + fr;
                const int h = col >> 6, d = col & 63;
                if (!vmode) {
#pragma unroll
                    for (int r = 0; r < 4; ++r)
                        Out[(((size_t)b * NH + h) * TSEQ + (t0 + r)) * HD + d] =
                            f2bf(acc[mt][nt][r] * qs);
                } else {
                    ushort4 pk;
                    pk.x = f2bf(acc[mt][nt][0]); pk.y = f2bf(acc[mt][nt][1]);
                    pk.z = f2bf(acc[mt][nt][2]); pk.w = f2bf(acc[mt][nt][3]);
                    *(ushort4*)&Out[(((size_t)b * NH + h) * HD + d) * TSEQ + t0] = pk;
                }
            }
        }
    }
}

// ---------------------------------------------------------------------------
// Sliding-window flash attention, bf16 MFMA, SWAPPED operands:
//   S^T[key][q] = mfma(K_frag, Q_frag)  -> lane owns whole q-rows in-lane
//   O^T[d][q]   = mfma(V_frag, P_frag)  -> softmax stats stay in-lane
// Block = 128 q-rows of one (b,h); 4 waves x 32 q-rows. K tile 64 keys.
// K staged [key][d], V (pre-transposed [b,h,d,t]) staged [d][key]; P via
// per-wave LDS strip [q][key]. fp32 online softmax, Q pre-scaled by 1/8.
// Grid: 512 blocks, XCD-chunked so each (b,h)'s K/V stays in one XCD's L2.
// ---------------------------------------------------------------------------
__global__ __launch_bounds__(256) void attn_mfma(
    const unsigned short* __restrict__ Qg, const unsigned short* __restrict__ Kg,
    const unsigned short* __restrict__ Vg, unsigned short* __restrict__ Y)
{
    __shared__ unsigned short Ks[64][72];      // [key][d]
    __shared__ unsigned short Vs[64][72];      // [d][key]
    __shared__ unsigned short Ps[4][32][72];   // per-wave [q][key]

    const int tid  = threadIdx.x;
    const int lane = tid & 63;
    const int w    = tid >> 6;

    // XCD-chunked bijective remap (512 blocks, 8 XCDs, 64 per XCD)
    const int blk = blockIdx.x;
    const int wg  = (blk & 7) * 64 + (blk >> 3);
    const int bh  = wg >> 4;                   // 0..31
    const int q0  = (wg & 15) * QBLK;          // 0..1920

    const unsigned short* Qb = Qg + (size_t)bh * TSEQ * HD;
    const unsigned short* Kb = Kg + (size_t)bh * TSEQ * HD;
    const unsigned short* Vb = Vg + (size_t)bh * HD * TSEQ;   // [d][t]

    const int fr = lane & 15;      // q-col (B), or row (A)
    const int fg = lane >> 4;      // k-group

    const int wq0 = q0 + w * 32;   // this wave's first q-row

    // Q B-fragments in registers for the whole kernel: Q[q][d], pre-scaled.
    short8 qa[2][2];
#pragma unroll
    for (int mt = 0; mt < 2; ++mt)
#pragma unroll
        for (int kh = 0; kh < 2; ++kh)
            qa[mt][kh] = *(const short8*)&Qb[(size_t)(wq0 + mt * 16 + fr) * HD + kh * 32 + fg * 8];

    const f32x4 fz = {0.f, 0.f, 0.f, 0.f};
    f32x4 Oacc[2][4];              // [mt][dt]: O^T tile rows d, cols q
    float mrow[2], lsum[2];        // per-lane: q-row = wq0 + mt*16 + fr
#pragma unroll
    for (int mt = 0; mt < 2; ++mt) {
        mrow[mt] = -1e30f; lsum[mt] = 0.f;
#pragma unroll
        for (int dt = 0; dt < 4; ++dt) Oacc[mt][dt] = fz;
    }

    int kbeg = q0 - (WIN - 1); if (kbeg < 0) kbeg = 0; kbeg &= ~63;
    int kend = q0 + QBLK + (WIN - 1); if (kend > TSEQ) kend = TSEQ;

    // staging: 32 rows x 64 cols per half-tile; thread t -> rows sr, sr+32
    const int sr = tid >> 3;
    const int sc = (tid & 7) * 8;
    uint4 kreg0 = *(const uint4*)&Kb[(size_t)(kbeg + sr) * HD + sc];
    uint4 kreg1 = *(const uint4*)&Kb[(size_t)(kbeg + sr + 32) * HD + sc];
    uint4 vreg0 = *(const uint4*)&Vb[(size_t)sr * TSEQ + kbeg + sc];
    uint4 vreg1 = *(const uint4*)&Vb[(size_t)(sr + 32) * TSEQ + kbeg + sc];

    for (int k0 = kbeg; k0 < kend; k0 += 64) {
        if (k0 != kbeg) __syncthreads();
        *(uint4*)&Ks[sr][sc]      = kreg0;
        *(uint4*)&Ks[sr + 32][sc] = kreg1;
        *(uint4*)&Vs[sr][sc]      = vreg0;
        *(uint4*)&Vs[sr + 32][sc] = vreg1;
        __syncthreads();
        if (k0 + 64 < kend) {
            kreg0 = *(const uint4*)&Kb[(size_t)(k0 + 64 + sr) * HD + sc];
            kreg1 = *(const uint4*)&Kb[(size_t)(k0 + 96 + sr) * HD + sc];
            vreg0 = *(const uint4*)&Vb[(size_t)sr * TSEQ + k0 + 64 + sc];
            vreg1 = *(const uint4*)&Vb[(size_t)(sr + 32) * TSEQ + k0 + 64 + sc];
        }

        // K A-fragments (shared across both mt)
        short8 ka[4][2];
#pragma unroll
        for (int kt = 0; kt < 4; ++kt)
#pragma unroll
            for (int kh = 0; kh < 2; ++kh)
                ka[kt][kh] = *(const short8*)&Ks[kt * 16 + fr][kh * 32 + fg * 8];

        // S^T = K.Q^T : lane holds, per mt, 16 scores of q-row (wq0+mt*16+fr)
        // at keys k0 + kt*16 + fg*4 + r.
        f32x4 S[2][4];
#pragma unroll
        for (int mt = 0; mt < 2; ++mt)
#pragma unroll
            for (int kt = 0; kt < 4; ++kt) {
                f32x4 s = fz;
                s = mfma16(ka[kt][0], qa[mt][0], s);
                s = mfma16(ka[kt][1], qa[mt][1], s);
                S[mt][kt] = s;
            }

        // fully-unmasked interior tile for ALL rows of this block?
        const bool full = (k0 >= q0 - 384) && (k0 <= q0 + 448);

#pragma unroll
        for (int mt = 0; mt < 2; ++mt) {
            const int q = wq0 + mt * 16 + fr;
            float sv[16];
#pragma unroll
            for (int kt = 0; kt < 4; ++kt)
#pragma unroll
                for (int r = 0; r < 4; ++r) {
                    float v = S[mt][kt][r];
                    if (!full) {
                        const int key = k0 + kt * 16 + fg * 4 + r;
                        const bool ok = (unsigned)(q - key + (WIN - 1)) < (unsigned)(2 * WIN - 1);
                        v = ok ? v : -1e30f;
                    }
                    sv[kt * 4 + r] = v;
                }
            // in-lane max over 16, then across the 4 fg groups
            float mx = sv[0];
#pragma unroll
            for (int i = 1; i < 16; ++i) mx = fmaxf(mx, sv[i]);
            mx = fmaxf(mx, __shfl_xor(mx, 16));
            mx = fmaxf(mx, __shfl_xor(mx, 32));
            const float mnew = fmaxf(mrow[mt], mx);
            const float f = __expf(mrow[mt] - mnew);
            float p[16], ps = 0.f;
            if (full) {
#pragma unroll
                for (int i = 0; i < 16; ++i) { p[i] = __expf(sv[i] - mnew); ps += p[i]; }
            } else {
#pragma unroll
                for (int i = 0; i < 16; ++i) {
                    p[i] = (sv[i] > -1e29f) ? __expf(sv[i] - mnew) : 0.f;
                    ps += p[i];
                }
            }
            ps += __shfl_xor(ps, 16);
            ps += __shfl_xor(ps, 32);
            lsum[mt] = lsum[mt] * f + ps;
            mrow[mt] = mnew;
            // rescale O^T columns (q in-lane) by f
#pragma unroll
            for (int dt = 0; dt < 4; ++dt) {
                f32x4 t = Oacc[mt][dt];
                t[0] *= f; t[1] *= f; t[2] *= f; t[3] *= f;
                Oacc[mt][dt] = t;
            }
            // P -> per-wave strip [q][key], 4 consecutive keys per b64 write
#pragma unroll
            for (int kt = 0; kt < 4; ++kt) {
                ushort4 pk;
                pk.x = f2bf(p[kt * 4 + 0]); pk.y = f2bf(p[kt * 4 + 1]);
                pk.z = f2bf(p[kt * 4 + 2]); pk.w = f2bf(p[kt * 4 + 3]);
                *(ushort4*)&Ps[w][mt * 16 + fr][kt * 16 + fg * 4] = pk;
            }
        }

        // O^T += V^T . P : A = V^T[d][key] from Vs, B = P[q][key] from Ps
#pragma unroll
        for (int kh = 0; kh < 2; ++kh) {
            short8 pb[2], va[4];
#pragma unroll
            for (int mt = 0; mt < 2; ++mt)
                pb[mt] = *(const short8*)&Ps[w][mt * 16 + fr][kh * 32 + fg * 8];
#pragma unroll
            for (int dt = 0; dt < 4; ++dt)
                va[dt] = *(const short8*)&Vs[dt * 16 + fr][kh * 32 + fg * 8];
#pragma unroll
            for (int mt = 0; mt < 2; ++mt)
#pragma unroll
                for (int dt = 0; dt < 4; ++dt)
                    Oacc[mt][dt] = mfma16(va[dt], pb[mt], Oacc[mt][dt]);
        }
    }

    // epilogue: normalize, store y [B,T,C] bf16. Lane's cols: q = wq0+mt*16+fr,
    // rows: d = dt*16 + fg*4 + r (4 consecutive d -> ushort4).
    const int b = bh >> 4, h = bh & 15;
#pragma unroll
    for (int mt = 0; mt < 2; ++mt) {
        const float inv = 1.f / lsum[mt];
        const int t = wq0 + mt * 16 + fr;
        unsigned short* dst = &Y[(size_t)(b * TSEQ + t) * CDIM + h * HD];
#pragma unroll
        for (int dt = 0; dt < 4; ++dt) {
            ushort4 pk;
            pk.x = f2bf(Oacc[mt][dt][0] * inv);
            pk.y = f2bf(Oacc[mt][dt][1] * inv);
            pk.z = f2bf(Oacc[mt][dt][2] * inv);
            pk.w = f2bf(Oacc[mt][dt][3] * inv);
            *(ushort4*)&dst[dt * 16 + fg * 4] = pk;
        }
    }
}

// ---------------------------------------------------------------------------
extern "C" void kernel_launch(void* const* d_in, const int* in_sizes, int n_in,
                              void* d_out, int out_size, void* d_ws, size_t ws_size,
                              hipStream_t stream)
{
    const float* x  = (const float*)d_in[0];
    const float* Wq = (const float*)d_in[1];
    const float* Wk = (const float*)d_in[2];
    const float* Wv = (const float*)d_in[3];
    const float* Wo = (const float*)d_in[4];
    float* out = (float*)d_out;

    const size_t XN = (size_t)MROWS * CDIM;   // 4M elems
    unsigned short* Qb = (unsigned short*)d_ws;   // [b,h,t,d], pre-scaled 1/8
    unsigned short* Kb = Qb + XN;                 // [b,h,t,d]
    unsigned short* Vb = Kb + XN;                 // [b,h,d,t]
    unsigned short* Yb = Vb + XN;                 // [b,t,c]

    // 1) QKV projections straight from fp32 (convert folded into staging)
    gemm_bf16<1, 1, 1><<<dim3(MROWS / 128, CDIM / 128, 3), 256, 0, stream>>>(
        x, Wq, Wk, Wv, Qb, Kb, Vb);
    // 2) sliding-window attention (swapped-operand MFMA, XCD-chunked grid)
    attn_mfma<<<dim3((TSEQ / QBLK) * BATCH * NH), 256, 0, stream>>>(Qb, Kb, Vb, Yb);
    // 3) output projection -> fp32 out (A bf16, W fp32)
    gemm_bf16<0, 0, 1><<<dim3(MROWS / 128, CDIM / 128, 1), 256, 0, stream>>>(
        Yb, Wo, Wo, Wo, out, out, out);
}

// Round 11
// 182.263 us; speedup vs baseline: 4.2226x; 1.0985x over previous
//
#include <hip/hip_runtime.h>

// Problem constants: B=2, T=2048, C=1024, H=16, hd=64, window=512.
#define BATCH 2
#define TSEQ  2048
#define CDIM  1024
#define NH    16
#define HD    64
#define WIN   512
#define MROWS (BATCH * TSEQ)   // 4096
#define QBLK  128              // q-rows per attention block

typedef __attribute__((ext_vector_type(8))) short short8;   // 8 bf16 (4 VGPRs)
typedef __attribute__((ext_vector_type(4))) float f32x4;

static __device__ __forceinline__ unsigned short f2bf(float f) {
    union { float f; unsigned u; } v; v.f = f;
    unsigned r = v.u + 0x7FFFu + ((v.u >> 16) & 1u);   // RNE
    return (unsigned short)(r >> 16);
}

static __device__ __forceinline__ f32x4 mfma16(short8 a, short8 b, f32x4 c) {
    return __builtin_amdgcn_mfma_f32_16x16x32_bf16(a, b, c, 0, 0, 0);
}

// async global->LDS, 16B per lane; LDS dest = wave-uniform base + lane*16
static __device__ __forceinline__ void gld16(const void* g, void* l) {
    __builtin_amdgcn_global_load_lds(
        (const __attribute__((address_space(1))) unsigned int*)g,
        (__attribute__((address_space(3))) unsigned int*)l, 16, 0, 0);
}

// ---------------------------------------------------------------------------
// fp32 -> bf16 conversion for x and the four weight matrices (8M elems, 8/thr)
// ---------------------------------------------------------------------------
__global__ __launch_bounds__(256) void convert_inputs(
    const float* __restrict__ x,  const float* __restrict__ wq,
    const float* __restrict__ wk, const float* __restrict__ wv,
    const float* __restrict__ wo,
    unsigned short* __restrict__ xb,  unsigned short* __restrict__ wqb,
    unsigned short* __restrict__ wkb, unsigned short* __restrict__ wvb,
    unsigned short* __restrict__ wob)
{
    const long i8 = (long)(blockIdx.x * 256 + threadIdx.x) * 8;
    const long XN = (long)MROWS * CDIM;      // 4M
    const long WN = (long)CDIM * CDIM;       // 1M
    const float* src; unsigned short* dst; long off;
    if (i8 < XN) { src = x; dst = xb; off = i8; }
    else {
        long j = i8 - XN; int w = (int)(j / WN); off = j - (long)w * WN;
        src = (w == 0) ? wq : (w == 1) ? wk : (w == 2) ? wv : wo;
        dst = (w == 0) ? wqb : (w == 1) ? wkb : (w == 2) ? wvb : wob;
    }
    const float4 a = *(const float4*)&src[off];
    const float4 b = *(const float4*)&src[off + 4];
    uint4 o;
    o.x = f2bf(a.x) | ((unsigned)f2bf(a.y) << 16);
    o.y = f2bf(a.z) | ((unsigned)f2bf(a.w) << 16);
    o.z = f2bf(b.x) | ((unsigned)f2bf(b.y) << 16);
    o.w = f2bf(b.z) | ((unsigned)f2bf(b.w) << 16);
    *(uint4*)&dst[off] = o;
}

// ---------------------------------------------------------------------------
// bf16 MFMA GEMM, global_load_lds staging: C[m,n] = sum_k A[m,k]*W[n,k].
// 128x128 tile, BK=32, 4 waves, 4x4 frags of 16x16x32 per wave.
// LDS layout: linear [row][4 chunks of 8 bf16], chunk slot XOR-swizzled by
// ((row>>1)&3); the INVERSE swizzle is applied to the per-lane GLOBAL source
// address (m173 pattern) so gload_lds's linear lane->dest works. ds_read of
// fragments lands conflict-free (each 8-lane group hits 8 distinct quads).
// MODE 0: fp32 row-major out [M,1024] (z=0 only)
// MODE 1: bf16 out; z=0 -> Q [b,h,t,d] scaled by 1/8; z=1 -> K [b,h,t,d];
//         z=2 -> V transposed [b,h,d,t].
// ---------------------------------------------------------------------------
template <int MODE>
__global__ __launch_bounds__(256) void gemm_bf16(
    const unsigned short* __restrict__ A,
    const unsigned short* __restrict__ W0, const unsigned short* __restrict__ W1,
    const unsigned short* __restrict__ W2,
    void* __restrict__ O0, void* __restrict__ O1, void* __restrict__ O2)
{
    constexpr int KD = CDIM;
    __shared__ unsigned short As[128 * 32];
    __shared__ unsigned short Bs[128 * 32];

    const int tid  = threadIdx.x;
    const int lane = tid & 63;
    const int w    = tid >> 6;
    const int wm   = (w >> 1) * 64;
    const int wn   = (w & 1) * 64;
    const int m0   = blockIdx.x * 128;
    const int n0   = blockIdx.y * 128;
    const unsigned short* Wm = (blockIdx.z == 0) ? W0 : (blockIdx.z == 1) ? W1 : W2;

    // staging geometry: wave w covers rows [w*16, w*16+16) (+64 for 2nd issue);
    // lane l -> row w*16 + (l>>2), slot l&3; source chunk = slot ^ ((row>>1)&3)
    const int srow = w * 16 + (lane >> 2);
    const int sch  = (lane & 3) ^ ((srow >> 1) & 3);
    const unsigned short* gA = A  + (size_t)(m0 + srow) * KD + sch * 8;
    const unsigned short* gB = Wm + (size_t)(n0 + srow) * KD + sch * 8;
    unsigned short* lA = As + (size_t)(w * 16) * 32;   // wave-uniform
    unsigned short* lB = Bs + (size_t)(w * 16) * 32;

    // fragment read offsets (elements), constant per thread
    const int fr = lane & 15;
    const int fg = lane >> 4;
    int aoff[4], boff[4];
#pragma unroll
    for (int i = 0; i < 4; ++i) {
        const int Ra = wm + i * 16 + fr;
        aoff[i] = Ra * 32 + (fg ^ ((Ra >> 1) & 3)) * 8;
        const int Rb = wn + i * 16 + fr;
        boff[i] = Rb * 32 + (fg ^ ((Rb >> 1) & 3)) * 8;
    }

    const f32x4 fz = {0.f, 0.f, 0.f, 0.f};
    f32x4 acc[4][4];
#pragma unroll
    for (int i = 0; i < 4; ++i)
#pragma unroll
        for (int j = 0; j < 4; ++j) acc[i][j] = fz;

    // stage tile 0
    gld16(gA, lA);  gld16(gA + (size_t)64 * KD, lA + 64 * 32);
    gld16(gB, lB);  gld16(gB + (size_t)64 * KD, lB + 64 * 32);

    for (int kt = 0; kt < KD / 32; ++kt) {
        __syncthreads();   // drains vmcnt -> staged tile kt visible
        short8 af[4], bf[4];
#pragma unroll
        for (int mt = 0; mt < 4; ++mt) af[mt] = *(const short8*)&As[aoff[mt]];
#pragma unroll
        for (int nt = 0; nt < 4; ++nt) bf[nt] = *(const short8*)&Bs[boff[nt]];
#pragma unroll
        for (int mt = 0; mt < 4; ++mt)
#pragma unroll
            for (int nt = 0; nt < 4; ++nt)
                acc[mt][nt] = mfma16(af[mt], bf[nt], acc[mt][nt]);
        if (kt + 1 < KD / 32) {
            __syncthreads();   // all waves done reading LDS
            const int ko = (kt + 1) * 32;
            gld16(gA + ko, lA);  gld16(gA + ko + (size_t)64 * KD, lA + 64 * 32);
            gld16(gB + ko, lB);  gld16(gB + ko + (size_t)64 * KD, lB + 64 * 32);
        }
    }

    const int fgr = lane >> 4;
    if constexpr (MODE == 0) {
        float* Out = (float*)O0;
#pragma unroll
        for (int mt = 0; mt < 4; ++mt) {
            const int row0 = m0 + wm + mt * 16 + fgr * 4;
#pragma unroll
            for (int nt = 0; nt < 4; ++nt) {
                const int col = n0 + wn + nt * 16 + fr;
#pragma unroll
                for (int r = 0; r < 4; ++r)
                    Out[(size_t)(row0 + r) * CDIM + col] = acc[mt][nt][r];
            }
        }
    } else {
        unsigned short* Out = (unsigned short*)((blockIdx.z == 0) ? O0 : (blockIdx.z == 1) ? O1 : O2);
        const bool vmode = (blockIdx.z == 2);
        const float qs = (blockIdx.z == 0) ? 0.125f : 1.0f;   // fold 1/sqrt(hd) into Q
#pragma unroll
        for (int mt = 0; mt < 4; ++mt) {
            const int row0 = m0 + wm + mt * 16 + fgr * 4;
            const int b  = row0 >> 11;           // / TSEQ
            const int t0 = row0 & (TSEQ - 1);
#pragma unroll
            for (int nt = 0; nt < 4; ++nt) {
                const int col = n0 + wn + nt * 16 + fr;
                const int h = col >> 6, d = col & 63;
                if (!vmode) {
#pragma unroll
                    for (int r = 0; r < 4; ++r)
                        Out[(((size_t)b * NH + h) * TSEQ + (t0 + r)) * HD + d] =
                            f2bf(acc[mt][nt][r] * qs);
                } else {
                    ushort4 pk;
                    pk.x = f2bf(acc[mt][nt][0]); pk.y = f2bf(acc[mt][nt][1]);
                    pk.z = f2bf(acc[mt][nt][2]); pk.w = f2bf(acc[mt][nt][3]);
                    *(ushort4*)&Out[(((size_t)b * NH + h) * HD + d) * TSEQ + t0] = pk;
                }
            }
        }
    }
}

// ---------------------------------------------------------------------------
// Sliding-window flash attention, bf16 MFMA, swapped operands, 8 waves/block.
//   S^T[key][q] = mfma(K_frag, Q_frag)  -> lane owns whole q-rows in-lane
//   O^T[d][q]   = mfma(V_frag, P_frag)  -> softmax stats stay in-lane
// Block = 128 q-rows of one (b,h); 8 waves x 16 q-rows -> per-wave softmax
// chain halved vs 4-wave and 2x waves/CU for latency hiding. K tile 64 keys,
// staged by all 512 threads (one uint4 each per operand), reg-prefetched.
// Grid: 512 blocks XCD-chunked so each (b,h)'s K/V stays in one XCD's L2.
// ---------------------------------------------------------------------------
__global__ __launch_bounds__(512, 4) void attn_mfma(
    const unsigned short* __restrict__ Qg, const unsigned short* __restrict__ Kg,
    const unsigned short* __restrict__ Vg, unsigned short* __restrict__ Y)
{
    __shared__ unsigned short Ks[64][72];      // [key][d]
    __shared__ unsigned short Vs[64][72];      // [d][key]
    __shared__ unsigned short Ps[8][16][72];   // per-wave [q][key]

    const int tid  = threadIdx.x;
    const int lane = tid & 63;
    const int w    = tid >> 6;                 // 0..7

    // XCD-chunked bijective remap (512 blocks, 8 XCDs, 64 per XCD)
    const int blk = blockIdx.x;
    const int wg  = (blk & 7) * 64 + (blk >> 3);
    const int bh  = wg >> 4;                   // 0..31
    const int q0  = (wg & 15) * QBLK;          // 0..1920

    const unsigned short* Qb = Qg + (size_t)bh * TSEQ * HD;
    const unsigned short* Kb = Kg + (size_t)bh * TSEQ * HD;
    const unsigned short* Vb = Vg + (size_t)bh * HD * TSEQ;   // [d][t]

    const int fr = lane & 15;      // q-col (B) / row (A)
    const int fg = lane >> 4;      // k-group
    const int wq0 = q0 + w * 16;   // this wave's first q-row

    // Q B-fragments in registers (pre-scaled by 1/8 in the QKV epilogue)
    short8 qa[2];
#pragma unroll
    for (int kh = 0; kh < 2; ++kh)
        qa[kh] = *(const short8*)&Qb[(size_t)(wq0 + fr) * HD + kh * 32 + fg * 8];

    const f32x4 fz = {0.f, 0.f, 0.f, 0.f};
    f32x4 Oacc[4];
    float mrow = -1e30f, lsum = 0.f;
#pragma unroll
    for (int dt = 0; dt < 4; ++dt) Oacc[dt] = fz;

    int kbeg = q0 - (WIN - 1); if (kbeg < 0) kbeg = 0; kbeg &= ~63;
    int kend = q0 + QBLK + (WIN - 1); if (kend > TSEQ) kend = TSEQ;

    // staging: 64 rows x 64 cols, one uint4 per thread per operand
    const int sr = tid >> 3;            // 0..63
    const int sc = (tid & 7) * 8;
    uint4 kreg = *(const uint4*)&Kb[(size_t)(kbeg + sr) * HD + sc];
    uint4 vreg = *(const uint4*)&Vb[(size_t)sr * TSEQ + kbeg + sc];

    for (int k0 = kbeg; k0 < kend; k0 += 64) {
        if (k0 != kbeg) __syncthreads();
        *(uint4*)&Ks[sr][sc] = kreg;
        *(uint4*)&Vs[sr][sc] = vreg;
        __syncthreads();
        if (k0 + 64 < kend) {
            kreg = *(const uint4*)&Kb[(size_t)(k0 + 64 + sr) * HD + sc];
            vreg = *(const uint4*)&Vb[(size_t)sr * TSEQ + k0 + 64 + sc];
        }

        // K A-fragments
        short8 ka[4][2];
#pragma unroll
        for (int kt = 0; kt < 4; ++kt)
#pragma unroll
            for (int kh = 0; kh < 2; ++kh)
                ka[kt][kh] = *(const short8*)&Ks[kt * 16 + fr][kh * 32 + fg * 8];

        // S^T: lane holds 16 scores of q-row (wq0+fr) at keys k0+kt*16+fg*4+r
        f32x4 S[4];
#pragma unroll
        for (int kt = 0; kt < 4; ++kt) {
            f32x4 s = fz;
            s = mfma16(ka[kt][0], qa[0], s);
            s = mfma16(ka[kt][1], qa[1], s);
            S[kt] = s;
        }

        // fully-unmasked interior tile for ALL rows of this block?
        const bool full = (k0 >= q0 - 384) && (k0 <= q0 + 448);

        const int q = wq0 + fr;
        float sv[16];
#pragma unroll
        for (int kt = 0; kt < 4; ++kt)
#pragma unroll
            for (int r = 0; r < 4; ++r) {
                float v = S[kt][r];
                if (!full) {
                    const int key = k0 + kt * 16 + fg * 4 + r;
                    const bool ok = (unsigned)(q - key + (WIN - 1)) < (unsigned)(2 * WIN - 1);
                    v = ok ? v : -1e30f;
                }
                sv[kt * 4 + r] = v;
            }
        float mx = sv[0];
#pragma unroll
        for (int i = 1; i < 16; ++i) mx = fmaxf(mx, sv[i]);
        mx = fmaxf(mx, __shfl_xor(mx, 16));
        mx = fmaxf(mx, __shfl_xor(mx, 32));
        const float mnew = fmaxf(mrow, mx);
        const float f = __expf(mrow - mnew);
        float p[16], ps = 0.f;
        if (full) {
#pragma unroll
            for (int i = 0; i < 16; ++i) { p[i] = __expf(sv[i] - mnew); ps += p[i]; }
        } else {
#pragma unroll
            for (int i = 0; i < 16; ++i) {
                p[i] = (sv[i] > -1e29f) ? __expf(sv[i] - mnew) : 0.f;
                ps += p[i];
            }
        }
        ps += __shfl_xor(ps, 16);
        ps += __shfl_xor(ps, 32);
        lsum = lsum * f + ps;
        mrow = mnew;
#pragma unroll
        for (int dt = 0; dt < 4; ++dt) {
            f32x4 t = Oacc[dt];
            t[0] *= f; t[1] *= f; t[2] *= f; t[3] *= f;
            Oacc[dt] = t;
        }
        // P -> per-wave strip [q][key]
#pragma unroll
        for (int kt = 0; kt < 4; ++kt) {
            ushort4 pk;
            pk.x = f2bf(p[kt * 4 + 0]); pk.y = f2bf(p[kt * 4 + 1]);
            pk.z = f2bf(p[kt * 4 + 2]); pk.w = f2bf(p[kt * 4 + 3]);
            *(ushort4*)&Ps[w][fr][kt * 16 + fg * 4] = pk;
        }

        // O^T += V^T . P  (same-wave LDS RAW; compiler inserts lgkmcnt)
#pragma unroll
        for (int kh = 0; kh < 2; ++kh) {
            const short8 pb = *(const short8*)&Ps[w][fr][kh * 32 + fg * 8];
            short8 va[4];
#pragma unroll
            for (int dt = 0; dt < 4; ++dt)
                va[dt] = *(const short8*)&Vs[dt * 16 + fr][kh * 32 + fg * 8];
#pragma unroll
            for (int dt = 0; dt < 4; ++dt)
                Oacc[dt] = mfma16(va[dt], pb, Oacc[dt]);
        }
    }

    // epilogue: normalize, store y [B,T,C] bf16; lane col q = wq0+fr,
    // rows d = dt*16 + fg*4 + r (4 consecutive d -> ushort4)
    const int b = bh >> 4, h = bh & 15;
    const float inv = 1.f / lsum;
    const int t = wq0 + fr;
    unsigned short* dst = &Y[(size_t)(b * TSEQ + t) * CDIM + h * HD];
#pragma unroll
    for (int dt = 0; dt < 4; ++dt) {
        ushort4 pk;
        pk.x = f2bf(Oacc[dt][0] * inv);
        pk.y = f2bf(Oacc[dt][1] * inv);
        pk.z = f2bf(Oacc[dt][2] * inv);
        pk.w = f2bf(Oacc[dt][3] * inv);
        *(ushort4*)&dst[dt * 16 + fg * 4] = pk;
    }
}

// ---------------------------------------------------------------------------
extern "C" void kernel_launch(void* const* d_in, const int* in_sizes, int n_in,
                              void* d_out, int out_size, void* d_ws, size_t ws_size,
                              hipStream_t stream)
{
    const float* x  = (const float*)d_in[0];
    const float* Wq = (const float*)d_in[1];
    const float* Wk = (const float*)d_in[2];
    const float* Wv = (const float*)d_in[3];
    const float* Wo = (const float*)d_in[4];
    float* out = (float*)d_out;

    const size_t XN = (size_t)MROWS * CDIM;   // 4M elems
    const size_t WN = (size_t)CDIM * CDIM;    // 1M elems
    unsigned short* xb  = (unsigned short*)d_ws;
    unsigned short* wqb = xb  + XN;
    unsigned short* wkb = wqb + WN;
    unsigned short* wvb = wkb + WN;
    unsigned short* wob = wvb + WN;
    unsigned short* Qb  = wob + WN;           // [b,h,t,d], pre-scaled 1/8
    unsigned short* Kb  = Qb  + XN;           // [b,h,t,d]
    unsigned short* Vb  = Kb  + XN;           // [b,h,d,t]
    unsigned short* Yb  = Vb  + XN;           // [b,t,c]

    // 1) fp32 -> bf16 (x + 4 weight matrices)
    convert_inputs<<<dim3(4096), 256, 0, stream>>>(x, Wq, Wk, Wv, Wo,
                                                   xb, wqb, wkb, wvb, wob);
    // 2) QKV projections (z: 0=Q,1=K,2=V-transposed), gload_lds staging
    gemm_bf16<1><<<dim3(MROWS / 128, CDIM / 128, 3), 256, 0, stream>>>(
        xb, wqb, wkb, wvb, Qb, Kb, Vb);
    // 3) sliding-window attention (8 waves/block, XCD-chunked grid)
    attn_mfma<<<dim3((TSEQ / QBLK) * BATCH * NH), 512, 0, stream>>>(Qb, Kb, Vb, Yb);
    // 4) output projection -> fp32 out
    gemm_bf16<0><<<dim3(MROWS / 128, CDIM / 128, 1), 256, 0, stream>>>(
        Yb, wob, wob, wob, out, out, out);
}